// Round 20
// baseline (52.236 us; speedup 1.0000x reference)
//
#include <hip/hip_runtime.h>
#include <hip/hip_bf16.h>

#define N_LATENT 64
#define N_OUT    64
#define CAP      256   // rows/sample capacity: mean 65.5, sd ~8 -> 23 sigma
#define TPS      16    // tile-slots per sample = CAP/16

typedef __attribute__((ext_vector_type(8))) _Float16 f16x8;
typedef __attribute__((ext_vector_type(4))) float    f32x4;

union U4H8 { uint4 u4; f16x8 h8; };

// ---- Kernel 1: zero cursors + pre-convert A[s] to f16 B-fragment layout ----
// One block per sample. Same fragment math as the proven round-16/17 LDS
// staging, but written once to ws (8 KB/sample) instead of once per block.
// Also zeroes cursor[s] (replaces the hipMemsetAsync node).
__global__ __launch_bounds__(256) void prep_kernel(
    const float* __restrict__ amat,
    int*  __restrict__ cursor,
    uint* __restrict__ bfrag)
{
    const int s    = blockIdx.x;
    const int tid  = threadIdx.x;
    const int lane = tid & 63;
    const int wave = tid >> 6;

    if (tid == 0) cursor[s] = 0;

    const float* __restrict__ Ag = amat + (size_t)s * (N_LATENT * N_OUT);
    uint* __restrict__ bf = bfrag + (size_t)s * 2048;   // 8 KB / sample

    for (int c = wave; c < 8; c += 4) {                 // c = kk*4 + nt
        const int kk  = c >> 2;
        const int nt  = c & 3;
        const int kb  = kk * 32 + (lane >> 4) * 8;      // 8 contiguous k
        const int col = nt * 16 + (lane & 15);
        U4H8 x;
#pragma unroll
        for (int j = 0; j < 8; ++j)
            x.h8[j] = (_Float16)Ag[(kb + j) * N_OUT + col];
        *((uint4*)&bf[(c * 64 + lane) * 4]) = x.u4;
    }
}

// ---- Kernel 2: ONE pass over sid builds per-sample row lists ----
__global__ void build_lists_kernel(const int* __restrict__ sid,
                                   int* __restrict__ cursor,
                                   int* __restrict__ list,
                                   int n4)
{
    const int i = blockIdx.x * blockDim.x + threadIdx.x;
    if (i < n4) {
        const int4 v = ((const int4*)sid)[i];
        int p;
        p = atomicAdd(&cursor[v.x], 1); if (p < CAP) list[v.x * CAP + p] = 4 * i;
        p = atomicAdd(&cursor[v.y], 1); if (p < CAP) list[v.y * CAP + p] = 4 * i + 1;
        p = atomicAdd(&cursor[v.z], 1); if (p < CAP) list[v.z * CAP + p] = 4 * i + 2;
        p = atomicAdd(&cursor[v.w], 1); if (p < CAP) list[v.w * CAP + p] = 4 * i + 3;
    }
}

// ---- Kernel 3: ONE WAVE per 16-row tile; no LDS, no barriers ----
// Block p -> sample p>>4, tile slot p&15 (covers CAP=256 rows). Empty slots
// exit after one L2 read. B-frags are 8 coalesced uint4 loads from the
// pre-converted buffer. Fragment k-map/C-map and per-row math byte-identical
// to the passing round-16/17 kernel (absmax 0.25).
__global__ __launch_bounds__(64) void decoder_mfma_kernel(
    const float* __restrict__ u,
    const float* __restrict__ offsets,
    const int*   __restrict__ cursor,
    const int*   __restrict__ list,
    const uint*  __restrict__ bfrag,
    float*       __restrict__ out)
{
    const int p    = blockIdx.x;
    const int s    = p >> 4;
    const int t    = p & (TPS - 1);
    const int lane = threadIdx.x;               // 0..63

    int n = cursor[s];
    n = (n < CAP) ? n : CAP;
    if (t * 16 >= n) return;

    const int*  __restrict__ lst = list + s * CAP;
    const uint* __restrict__ bf  = bfrag + (size_t)s * 2048;

    // ---- A fragment: 16 rows (lane&15), k-chunk (lane>>4)*8 ----
    const int ridx = t * 16 + (lane & 15);
    const int brow = lst[(ridx < n) ? ridx : 0];        // pad: row list[0]
    const float* __restrict__ up =
        u + (size_t)brow * N_LATENT + ((lane >> 4) * 8);
    f16x8 a0, a1;
    {
        const float4 p0 = *(const float4*)(up);
        const float4 p1 = *(const float4*)(up + 4);
        const float4 p2 = *(const float4*)(up + 32);    // kk=1: k += 32
        const float4 p3 = *(const float4*)(up + 36);
        a0[0] = (_Float16)p0.x; a0[1] = (_Float16)p0.y;
        a0[2] = (_Float16)p0.z; a0[3] = (_Float16)p0.w;
        a0[4] = (_Float16)p1.x; a0[5] = (_Float16)p1.y;
        a0[6] = (_Float16)p1.z; a0[7] = (_Float16)p1.w;
        a1[0] = (_Float16)p2.x; a1[1] = (_Float16)p2.y;
        a1[2] = (_Float16)p2.z; a1[3] = (_Float16)p2.w;
        a1[4] = (_Float16)p3.x; a1[5] = (_Float16)p3.y;
        a1[6] = (_Float16)p3.z; a1[7] = (_Float16)p3.w;
    }

    // ---- epilogue row indices (C map: row=(lane>>4)*4+r) ----
    int  b2[4]; bool val[4];
#pragma unroll
    for (int r = 0; r < 4; ++r) {
        const int ridx2 = t * 16 + (lane >> 4) * 4 + r;
        val[r] = (ridx2 < n);
        b2[r]  = lst[val[r] ? ridx2 : 0];
    }

#pragma unroll
    for (int nt = 0; nt < 4; ++nt) {
        const float off = offsets[(size_t)s * N_OUT + nt * 16 + (lane & 15)];
        U4H8 b0, b1;
        b0.u4 = *((const uint4*)&bf[((0 * 4 + nt) * 64 + lane) * 4]);
        b1.u4 = *((const uint4*)&bf[((1 * 4 + nt) * 64 + lane) * 4]);
        f32x4 acc = {0.f, 0.f, 0.f, 0.f};
        acc = __builtin_amdgcn_mfma_f32_16x16x32_f16(a0, b0.h8, acc, 0, 0, 0);
        acc = __builtin_amdgcn_mfma_f32_16x16x32_f16(a1, b1.h8, acc, 0, 0, 0);

        const int col = nt * 16 + (lane & 15);
#pragma unroll
        for (int r = 0; r < 4; ++r) {
            if (val[r]) {
                const size_t idx = (size_t)b2[r] * N_OUT + col;
                out[idx] = u[idx] + acc[r] + off;
            }
        }
    }
}

extern "C" void kernel_launch(void* const* d_in, const int* in_sizes, int n_in,
                              void* d_out, int out_size, void* d_ws, size_t ws_size,
                              hipStream_t stream)
{
    const float* u       = (const float*)d_in[0];
    const int*   sid     = (const int*)d_in[1];
    const float* amat    = (const float*)d_in[2];
    const float* offsets = (const float*)d_in[3];
    float*       out     = (float*)d_out;

    const int batch    = in_sizes[0] / N_LATENT;            // 65536
    const int n_sample = in_sizes[2] / (N_LATENT * N_OUT);  // 1000

    // ws layout: cursor (n_sample ints) | list (n_sample*CAP ints)
    //            | bfrag (n_sample*2048 uints, 16B-aligned by construction)
    int*  cursor = (int*)d_ws;
    int*  list   = cursor + n_sample;
    uint* bfrag  = (uint*)(list + (size_t)n_sample * CAP);

    prep_kernel<<<n_sample, 256, 0, stream>>>(amat, cursor, bfrag);

    const int n4 = batch / 4;
    build_lists_kernel<<<(n4 + 255) / 256, 256, 0, stream>>>(
        sid, cursor, list, n4);

    decoder_mfma_kernel<<<n_sample * TPS, 64, 0, stream>>>(
        u, offsets, cursor, list, bfrag, out);
}

// Round 21
// 30.008 us; speedup vs baseline: 1.7407x; 1.7407x over previous
//
#include <hip/hip_runtime.h>
#include <hip/hip_bf16.h>

#define N_LATENT 64
#define N_OUT    64
#define CAP      256   // rows/sample capacity: mean 65.5, sd ~8 -> 23 sigma
#define CSTRIDE  16    // cursor padded to 1 cacheline (64 B) per sample:
                       // 1000 contiguous ints = 63 lines shared by 16 samples
                       // -> 262K contended atomic RMWs false-sharing across
                       // 8 XCDs. Padding isolates each sample's line.

typedef __attribute__((ext_vector_type(8))) _Float16 f16x8;
typedef __attribute__((ext_vector_type(4))) float    f32x4;

union U4H8 { uint4 u4; f16x8 h8; };

// ---- Kernel A: ONE pass over sid builds per-sample row lists ----
__global__ void build_lists_kernel(const int* __restrict__ sid,
                                   int* __restrict__ cursor,
                                   int* __restrict__ list,
                                   int n4)
{
    const int i = blockIdx.x * blockDim.x + threadIdx.x;
    if (i < n4) {
        const int4 v = ((const int4*)sid)[i];
        int p;
        p = atomicAdd(&cursor[v.x * CSTRIDE], 1); if (p < CAP) list[v.x * CAP + p] = 4 * i;
        p = atomicAdd(&cursor[v.y * CSTRIDE], 1); if (p < CAP) list[v.y * CAP + p] = 4 * i + 1;
        p = atomicAdd(&cursor[v.z * CSTRIDE], 1); if (p < CAP) list[v.z * CAP + p] = 4 * i + 2;
        p = atomicAdd(&cursor[v.w * CSTRIDE], 1); if (p < CAP) list[v.w * CAP + p] = 4 * i + 3;
    }
}

// ---- Kernel B: one block (256 thr = 4 waves) per sample; MFMA compute ----
// Exact round-16 champion (40.5 us total): B-frags of A[s] (f16) staged once
// to LDS (8 KB); wave w runs tiles w, w+4, ... Per 16-row tile: 8 MFMA
// (4 n-tiles x 2 k-halves of 16x16x32). k-map identical for A/B fragments
// (self-consistent bijection); C/D map col=lane&15, row=(lane>>4)*4+r.
// fp32 residual via u re-read in epilogue. absmax 0.25 (f16 inputs).
__global__ __launch_bounds__(256) void decoder_mfma_kernel(
    const float* __restrict__ u,
    const float* __restrict__ amat,
    const float* __restrict__ offsets,
    const int*   __restrict__ cursor,
    const int*   __restrict__ list,
    float*       __restrict__ out)
{
    __shared__ uint Bf[8 * 64 * 4];            // (kk*4+nt, lane) -> 4 dwords

    const int s    = blockIdx.x;
    const int tid  = threadIdx.x;
    const int lane = tid & 63;
    const int wave = tid >> 6;                 // 0..3

    int n = cursor[s * CSTRIDE];
    n = (n < CAP) ? n : CAP;
    if (n == 0) return;                        // uniform exit, before barrier

    const float* __restrict__ Ag  = amat + (size_t)s * (N_LATENT * N_OUT);
    const int*   __restrict__ lst = list + s * CAP;

    // stage B fragments: combo c = kk*4+nt; wave w stages {w, w+4}
    for (int c = wave; c < 8; c += 4) {
        const int kk  = c >> 2;
        const int nt  = c & 3;
        const int kb  = kk * 32 + (lane >> 4) * 8;   // 8 contiguous k
        const int col = nt * 16 + (lane & 15);
        U4H8 x;
#pragma unroll
        for (int j = 0; j < 8; ++j)
            x.h8[j] = (_Float16)Ag[(kb + j) * N_OUT + col];
        *((uint4*)&Bf[(c * 64 + lane) * 4]) = x.u4;
    }
    __syncthreads();

    const int tiles = (n + 15) >> 4;

    float off_nt[4];
#pragma unroll
    for (int nt = 0; nt < 4; ++nt)
        off_nt[nt] = offsets[(size_t)s * N_OUT + nt * 16 + (lane & 15)];

    for (int t = wave; t < tiles; t += 4) {
        // A fragment: 16 rows (lane&15), k-chunk (lane>>4)*8
        const int ridx = t * 16 + (lane & 15);
        const int brow = lst[(ridx < n) ? ridx : 0];      // pad: row list[0]
        const float* __restrict__ up =
            u + (size_t)brow * N_LATENT + ((lane >> 4) * 8);
        f16x8 a0, a1;
        {
            const float4 p0 = *(const float4*)(up);
            const float4 p1 = *(const float4*)(up + 4);
            const float4 p2 = *(const float4*)(up + 32);  // kk=1: k += 32
            const float4 p3 = *(const float4*)(up + 36);
            a0[0] = (_Float16)p0.x; a0[1] = (_Float16)p0.y;
            a0[2] = (_Float16)p0.z; a0[3] = (_Float16)p0.w;
            a0[4] = (_Float16)p1.x; a0[5] = (_Float16)p1.y;
            a0[6] = (_Float16)p1.z; a0[7] = (_Float16)p1.w;
            a1[0] = (_Float16)p2.x; a1[1] = (_Float16)p2.y;
            a1[2] = (_Float16)p2.z; a1[3] = (_Float16)p2.w;
            a1[4] = (_Float16)p3.x; a1[5] = (_Float16)p3.y;
            a1[6] = (_Float16)p3.z; a1[7] = (_Float16)p3.w;
        }

        // epilogue row indices (C map: row=(lane>>4)*4+r)
        int  b2[4]; bool val[4];
#pragma unroll
        for (int r = 0; r < 4; ++r) {
            const int ridx2 = t * 16 + (lane >> 4) * 4 + r;
            val[r] = (ridx2 < n);
            b2[r]  = lst[val[r] ? ridx2 : 0];
        }

#pragma unroll
        for (int nt = 0; nt < 4; ++nt) {
            U4H8 b0, b1;
            b0.u4 = *((const uint4*)&Bf[((0 * 4 + nt) * 64 + lane) * 4]);
            b1.u4 = *((const uint4*)&Bf[((1 * 4 + nt) * 64 + lane) * 4]);
            f32x4 acc = {0.f, 0.f, 0.f, 0.f};
            acc = __builtin_amdgcn_mfma_f32_16x16x32_f16(a0, b0.h8, acc, 0, 0, 0);
            acc = __builtin_amdgcn_mfma_f32_16x16x32_f16(a1, b1.h8, acc, 0, 0, 0);

            const int col = nt * 16 + (lane & 15);
#pragma unroll
            for (int r = 0; r < 4; ++r) {
                if (val[r]) {
                    const size_t idx = (size_t)b2[r] * N_OUT + col;
                    out[idx] = u[idx] + acc[r] + off_nt[nt];
                }
            }
        }
    }
}

extern "C" void kernel_launch(void* const* d_in, const int* in_sizes, int n_in,
                              void* d_out, int out_size, void* d_ws, size_t ws_size,
                              hipStream_t stream)
{
    const float* u       = (const float*)d_in[0];
    const int*   sid     = (const int*)d_in[1];
    const float* amat    = (const float*)d_in[2];
    const float* offsets = (const float*)d_in[3];
    float*       out     = (float*)d_out;

    const int batch    = in_sizes[0] / N_LATENT;            // 65536
    const int n_sample = in_sizes[2] / (N_LATENT * N_OUT);  // 1000

    // ws layout (ints): [0, n_sample*CSTRIDE) padded cursors
    //                   | [n_sample*CSTRIDE, +n_sample*CAP) lists
    int* cursor = (int*)d_ws;
    int* list   = cursor + (size_t)n_sample * CSTRIDE;

    hipMemsetAsync(cursor, 0, (size_t)n_sample * CSTRIDE * sizeof(int), stream);

    const int n4 = batch / 4;
    build_lists_kernel<<<(n4 + 255) / 256, 256, 0, stream>>>(
        sid, cursor, list, n4);

    decoder_mfma_kernel<<<n_sample, 256, 0, stream>>>(
        u, amat, offsets, cursor, list, out);
}